// Round 8
// baseline (267.674 us; speedup 1.0000x reference)
//
#include <hip/hip_runtime.h>

// Problem constants (from reference)
#define BB   32
#define CC   64
#define HH   224
#define WW   224
#define H2   226
#define W2   226
#define HID  8

constexpr unsigned NPLANE   = BB * CC;       // 2048 planes
constexpr unsigned XHW      = HH * WW;       // 50176 floats / x plane
constexpr unsigned HW2      = H2 * W2;       // 51076 floats / out plane
constexpr unsigned F4PLANE  = HW2 / 4;       // 12769 f4 / out plane
constexpr unsigned GPP      = 50;            // 50*256 = 12800 >= 12769
constexpr unsigned NBORD    = NPLANE * HH;   // 458752 per border
constexpr size_t   NXTOT    = (size_t)NPLANE * XHW;

typedef float f4 __attribute__((ext_vector_type(4)));

struct WPtrs { const float* p[24]; };  // t[0..5] b[6..11] l[12..17] r[18..23]

// ---------------------------------------------------------------------------
// Kernel 1: padded copy via LDS realignment + NONTEMPORAL stores.
// Block (g,p): out plane p, flat out floats [g*1024, g*1024+1024).
// ---------------------------------------------------------------------------
__global__ __launch_bounds__(256) void pad_copy_k(const float* __restrict__ x,
                                                  float* __restrict__ out) {
    __shared__ __align__(16) float lds[1056];
    const unsigned t  = threadIdx.x;
    const unsigned g  = blockIdx.x;   // 0..49
    const unsigned p  = blockIdx.y;   // plane

    const unsigned o0 = g * 1024u;
    const unsigned h0 = o0 / 226u;
    const unsigned w0 = o0 - 226u * h0;
    int L0 = (int)(224u * h0 + w0) - 225 - 3;
    if (L0 < 0) L0 = 0;
    L0 &= ~3;

    const size_t pbase = (size_t)p * XHW;
    for (unsigned i = t; i < 264u; i += 256u) {
        size_t gi = pbase + (unsigned)L0 + 4u * i;
        if (gi > NXTOT - 4u) gi = NXTOT - 4u;   // clamp (garbage never consumed)
        const f4 v = *reinterpret_cast<const f4*>(x + gi);
        *reinterpret_cast<f4*>(&lds[4u * i]) = v;
    }
    __syncthreads();

    const unsigned f4i = g * 256u + t;
    if (f4i >= F4PLANE) return;
    const unsigned o = o0 + 4u * t;
    const unsigned h = o / 226u;
    const unsigned w = o - 226u * h;
    float vals[4];
#pragma unroll
    for (int e = 0; e < 4; ++e) {
        unsigned we = w + (unsigned)e;
        unsigned he = h;
        if (we >= 226u) { we -= 226u; ++he; }            // at most one row wrap
        const bool inter = ((he - 1u) < (unsigned)HH) & ((we - 1u) < (unsigned)WW);
        const int li = (int)(224u * he + we) - 225 - L0;
        const unsigned lic = inter ? (unsigned)li : 0u;
        const float vv = lds[lic];
        vals[e] = inter ? vv : 0.f;                      // ring -> 0 (corners final)
    }
    f4 res;
    res.x = vals[0]; res.y = vals[1]; res.z = vals[2]; res.w = vals[3];
    __builtin_nontemporal_store(
        res, reinterpret_cast<f4*>(out + (size_t)p * HW2) + f4i);
}

// ---------------------------------------------------------------------------
// MLP: s[2][3] -> scalar. W layout: [w1 48][b1 8][w2 64][b2 8][w3 8][b3 1]
// ---------------------------------------------------------------------------
__device__ __forceinline__ float mlp_eval(const float s[2][3],
                                          const float* __restrict__ W) {
    const float* W1  = W;
    const float* B1  = W + 48;
    const float* W2m = W + 56;
    const float* B2  = W + 120;
    const float* W3  = W + 128;
    const float  b3  = W[136];
    float y1[HID];
#pragma unroll
    for (int h = 0; h < HID; ++h) {
        float a = B1[h];
#pragma unroll
        for (int r = 0; r < 2; ++r)
#pragma unroll
            for (int k = 0; k < 3; ++k)
                a = fmaf(s[r][k], W1[h * 6 + r * 3 + k], a);
        y1[h] = fmaxf(a, 0.f);
    }
    float y2[HID];
#pragma unroll
    for (int o = 0; o < HID; ++o) {
        float a = B2[o];
#pragma unroll
        for (int h = 0; h < HID; ++h) a = fmaf(y1[h], W2m[o * 8 + h], a);
        y2[o] = fmaxf(a, 0.f);
    }
    float a = b3;
#pragma unroll
    for (int h = 0; h < HID; ++h) a = fmaf(y2[h], W3[h], a);
    return fmaxf(a, 0.f);
}

// top/bottom MLP at border position l (r0 = 0 top, 222 bottom); value that
// lands at padded (row 0/225, col l+1).
__device__ __forceinline__ float eval_tb(const float* __restrict__ xp,
                                         const float* __restrict__ W,
                                         unsigned l, unsigned r0) {
    float s[2][3];
#pragma unroll
    for (int r = 0; r < 2; ++r)
#pragma unroll
        for (int k = 0; k < 3; ++k) {
            unsigned xc = l + (unsigned)k - 1u;  // wrap-huge if OOB
            s[r][k] = (xc < (unsigned)WW) ? xp[(r0 + (unsigned)r) * WW + xc] : 0.f;
        }
    return mlp_eval(s, W);
}

// ---------------------------------------------------------------------------
// Kernel 2: all four borders in one dispatch. blockIdx.y: 0=top 1=bottom
// 2=left 3=right. No inter-family dependency: left/right recompute the 2
// corner-adjacent top/bottom values from x directly. Corners stay 0 (copy).
// ---------------------------------------------------------------------------
__global__ __launch_bounds__(256) void border_k(const float* __restrict__ x,
                                                float* __restrict__ out,
                                                WPtrs wp) {
    __shared__ float wts[4][137];
    const unsigned t = threadIdx.x;
#pragma unroll
    for (int br = 0; br < 4; ++br) {
        const float* const* b = wp.p + 6 * br;
        if (t < 48u) wts[br][t] = b[0][t];
        if (t < 64u) wts[br][56u + t] = b[2][t];
        if (t < 8u) {
            wts[br][48u + t]  = b[1][t];
            wts[br][120u + t] = b[3][t];
            wts[br][128u + t] = b[4][t];
        }
        if (t == 0u) wts[br][136] = b[5][0];
    }
    __syncthreads();

    const unsigned gid = blockIdx.x * 256u + t;
    const unsigned l   = gid % (unsigned)HH;
    const unsigned bc  = gid / (unsigned)HH;
    const unsigned fam = blockIdx.y;

    const float* xp = x + (size_t)bc * XHW;
    float*       op = out + (size_t)bc * HW2;

    if (fam < 2u) {
        const bool top = (fam == 0u);
        const float res = eval_tb(xp, wts[fam], l, top ? 0u : (unsigned)(HH - 2));
        op[(top ? 0u : (unsigned)(H2 - 1)) * W2 + l + 1u] = res;
    } else {
        const bool left    = (fam == 2u);
        const unsigned cc0 = left ? 0u : (unsigned)(WW - 2);  // x col base
        const unsigned oc0 = left ? 1u : (unsigned)(W2 - 3);  // padded col base
        float s[2][3];
#pragma unroll
        for (int k = 0; k < 3; ++k) {
            const unsigned pr = l + (unsigned)k;  // padded row l..l+2
            float v0, v1;
            if (pr == 0u) {                       // recompute 2 top values
                v0 = eval_tb(xp, wts[0], oc0 - 1u, 0u);
                v1 = eval_tb(xp, wts[0], oc0, 0u);
            } else if (pr == (unsigned)(H2 - 1)) {  // recompute 2 bottom values
                v0 = eval_tb(xp, wts[1], oc0 - 1u, (unsigned)(HH - 2));
                v1 = eval_tb(xp, wts[1], oc0, (unsigned)(HH - 2));
            } else {
                const float2 t2 = *reinterpret_cast<const float2*>(
                    xp + (pr - 1u) * (unsigned)WW + cc0);
                v0 = t2.x;
                v1 = t2.y;
            }
            s[0][k] = v0;
            s[1][k] = v1;
        }
        const float res = mlp_eval(s, wts[fam]);
        op[(l + 1u) * (unsigned)W2 + (left ? 0u : (unsigned)(W2 - 1))] = res;
    }
}

// ---------------------------------------------------------------------------
extern "C" void kernel_launch(void* const* d_in, const int* in_sizes, int n_in,
                              void* d_out, int out_size, void* d_ws,
                              size_t ws_size, hipStream_t stream) {
    const float* x = (const float*)d_in[0];
    WPtrs wp;
    for (int i = 0; i < 24; ++i) wp.p[i] = (const float*)d_in[1 + i];
    float* out = (float*)d_out;

    // 1) padded copy: interior + zero ring (corners final), NT stores
    pad_copy_k<<<dim3(GPP, NPLANE), dim3(256), 0, stream>>>(x, out);

    // 2) all four borders (read x only; overwrite non-corner ring)
    border_k<<<dim3(NBORD / 256u, 4), dim3(256), 0, stream>>>(x, out, wp);
}